// Round 3
// baseline (8217.985 us; speedup 1.0000x reference)
//
#include <hip/hip_runtime.h>
#include <math.h>

typedef unsigned short u16;
typedef float f32x4 __attribute__((ext_vector_type(4)));
typedef __bf16 bf16x8 __attribute__((ext_vector_type(8)));

#define DEVINL __device__ __forceinline__

DEVINL float sigm(float x) { return 1.f / (1.f + expf(-x)); }

DEVINL bf16x8 ldA(const u16* p) { return *(const bf16x8*)(const void*)p; }
DEVINL bf16x8 ldA(const float* p) {
    f32x4 a = *(const f32x4*)(const void*)p;
    f32x4 b = *(const f32x4*)(const void*)(p + 4);
    bf16x8 r;
    r[0] = (__bf16)a[0]; r[1] = (__bf16)a[1]; r[2] = (__bf16)a[2]; r[3] = (__bf16)a[3];
    r[4] = (__bf16)b[0]; r[5] = (__bf16)b[1]; r[6] = (__bf16)b[2]; r[7] = (__bf16)b[3];
    return r;
}
DEVINL f32x4 mfma_bf16(bf16x8 a, bf16x8 b, f32x4 c) {
    return __builtin_amdgcn_mfma_f32_16x16x32_bf16(a, b, c, 0, 0, 0);
}

// ---------------- fp32 -> bf16 convert with optional column pad ----------------
__global__ __launch_bounds__(256) void cvt_pad(
    const float* __restrict__ src, u16* __restrict__ dst, int rows, int scols, int dcols)
{
    int idx = blockIdx.x * 256 + threadIdx.x;
    if (idx >= rows * dcols) return;
    int r = idx / dcols, c = idx - r * dcols;
    float v = (c < scols) ? src[(size_t)r * scols + c] : 0.f;
    __bf16 h = (__bf16)v;
    u16 bits; __builtin_memcpy(&bits, &h, 2);
    dst[idx] = bits;
}

// ---------------- fused GRU step tile ----------------
// One wave: 16 batch rows x 16 h-dims x all 3 gates.
// r,z gates sum x- and h-parts in acc0/acc1; n-gate keeps x-part (acc2) and
// h-part (acc3) separate: n = tanh(xn + r*hn). Pointers pre-offset for dir d.
template<int HIPAD, int H, bool WOUT, typename XT>
DEVINL void gru_tile_fused(int s, int T, int d, int jblk, int mblk,
    const XT* __restrict__ x,                                   // [B,T,HIPAD]
    const u16* __restrict__ wih, const float* __restrict__ bih, // bf16 [3H,HIPAD], f32 [3H]
    const u16* __restrict__ whh, const float* __restrict__ bhh, // bf16 [3H,H],    f32 [3H]
    const u16* __restrict__ hbf_in, const float* __restrict__ hf_in,  // [128,H]
    u16* __restrict__ hbf_out, float* __restrict__ hf_out,
    const int* __restrict__ len, float* __restrict__ out, int tid)
{
    const int lane = tid & 63, wv = tid >> 6;
    const int l15 = lane & 15, quad = lane >> 4;
    const int m0 = mblk * 64 + wv * 16;
    const int j0 = jblk * 16;
    const int t = (d == 0) ? s : (T - 1 - s);

    f32x4 acc0{0,0,0,0}, acc1{0,0,0,0}, acc2{0,0,0,0}, acc3{0,0,0,0};

    const size_t ax = ((size_t)(m0 + l15) * T + t) * HIPAD;
    const size_t wr = (size_t)(j0 + l15) * HIPAD;
#pragma unroll 4
    for (int k0 = 0; k0 < HIPAD; k0 += 32) {
        bf16x8 a = ldA(x + ax + k0 + quad * 8);
        acc0 = mfma_bf16(a, ldA(wih + wr + k0 + quad * 8), acc0);
        acc1 = mfma_bf16(a, ldA(wih + wr + (size_t)H * HIPAD + k0 + quad * 8), acc1);
        acc2 = mfma_bf16(a, ldA(wih + wr + (size_t)2 * H * HIPAD + k0 + quad * 8), acc2);
    }
    const size_t ah = (size_t)(m0 + l15) * H;
    const size_t hr = (size_t)(j0 + l15) * H;
#pragma unroll 4
    for (int k0 = 0; k0 < H; k0 += 32) {
        bf16x8 a = ldA(hbf_in + ah + k0 + quad * 8);
        acc0 = mfma_bf16(a, ldA(whh + hr + k0 + quad * 8), acc0);
        acc1 = mfma_bf16(a, ldA(whh + hr + (size_t)H * H + k0 + quad * 8), acc1);
        acc3 = mfma_bf16(a, ldA(whh + hr + (size_t)2 * H * H + k0 + quad * 8), acc3);
    }
    const int j = j0 + l15;
    const float br  = bih[j]         + bhh[j];
    const float bz  = bih[H + j]     + bhh[H + j];
    const float bxn = bih[2 * H + j];
    const float bhn = bhh[2 * H + j];
#pragma unroll
    for (int r = 0; r < 4; r++) {
        int b = m0 + quad * 4 + r;
        float rg = sigm(acc0[r] + br);
        float zg = sigm(acc1[r] + bz);
        float ng = tanhf(acc2[r] + bxn + rg * (acc3[r] + bhn));
        float hp = hf_in[(size_t)b * H + j];
        bool valid = t < len[b];
        float hn2 = valid ? ((1.f - zg) * ng + zg * hp) : hp;
        hf_out[(size_t)b * H + j] = hn2;
        __bf16 hb = (__bf16)hn2; u16 hbits; __builtin_memcpy(&hbits, &hb, 2);
        hbf_out[(size_t)b * H + j] = hbits;
        if (WOUT)
            out[((size_t)b * T + t) * (2 * H) + (size_t)d * H + j] = valid ? hn2 : 0.f;
    }
}

// blocks 0..127: visual (d=bid>>6, jblk=(bid>>1)&31, mblk=bid&1)
// blocks 128..159: sentence forward (only launched while s<40)
__global__ __launch_bounds__(256) void gru_step_fused(int s,
    const float* __restrict__ gv,
    const u16* __restrict__ vwih, const float* __restrict__ vbih,
    const u16* __restrict__ vwhh, const float* __restrict__ vbhh,
    const u16* __restrict__ hvi_b, const float* __restrict__ hvi_f,
    u16* __restrict__ hvo_b, float* __restrict__ hvo_f,
    const int* __restrict__ v_len, float* __restrict__ out_vis,
    const u16* __restrict__ senpad, const u16* __restrict__ swihp,
    const float* __restrict__ sbih, const u16* __restrict__ swhhb, const float* __restrict__ sbhh,
    const u16* __restrict__ hsi_b, const float* __restrict__ hsi_f,
    u16* __restrict__ hso_b, float* __restrict__ hso_f,
    const int* __restrict__ lens)
{
    int bid = blockIdx.x;
    if (bid < 128) {
        int d = bid >> 6, jblk = (bid >> 1) & 31, mblk = bid & 1;
        gru_tile_fused<1024, 512, true, float>(s, 256, d, jblk, mblk,
            gv, vwih + (size_t)d * 1536 * 1024, vbih + d * 1536,
            vwhh + (size_t)d * 1536 * 512, vbhh + d * 1536,
            hvi_b + (size_t)d * 65536, hvi_f + (size_t)d * 65536,
            hvo_b + (size_t)d * 65536, hvo_f + (size_t)d * 65536,
            v_len, out_vis, threadIdx.x);
    } else {
        int b2 = bid - 128, jblk = b2 >> 1, mblk = b2 & 1;
        gru_tile_fused<320, 256, false, u16>(s, 40, 0, jblk, mblk,
            senpad, swihp, sbih, swhhb, sbhh,
            hsi_b, hsi_f, hso_b, hso_f, lens, (float*)nullptr, threadIdx.x);
    }
}

// ---------------- sen_fea: fwd final h + bwd single-step-from-zero ----------------
// Backward output at t=lens-1 is one step from h=0 (h stays 0 through the padded
// tail): hp-part = b_hh only; x-part computed directly from raw fp32 sen.
__global__ __launch_bounds__(256) void senfea_kernel(
    const float* __restrict__ hs_f, const float* __restrict__ sen,
    const float* __restrict__ swih, const float* __restrict__ sbih, const float* __restrict__ sbhh,
    const int* __restrict__ lens, float* __restrict__ out_sen)
{
    __shared__ float xs[304];
    int b = blockIdx.x, j = threadIdx.x;
    int t = lens[b] - 1;
    for (int k = j; k < 300; k += 256) xs[k] = sen[((size_t)b * 40 + t) * 300 + k];
    __syncthreads();

    out_sen[(size_t)b * 512 + j] = hs_f[(size_t)b * 256 + j];

    float dot[3];
#pragma unroll
    for (int g = 0; g < 3; g++) {
        const float* w = swih + (size_t)(768 + g * 256 + j) * 300;
        float sacc = 0.f;
        for (int k = 0; k < 300; k += 4) {
            f32x4 wv = *(const f32x4*)(const void*)(w + k);
#pragma unroll
            for (int q = 0; q < 4; q++) sacc += xs[k + q] * wv[q];
        }
        dot[g] = sacc + sbih[768 + g * 256 + j];
    }
    float rg = sigm(dot[0] + sbhh[768 + j]);
    float zg = sigm(dot[1] + sbhh[768 + 256 + j]);
    float ng = tanhf(dot[2] + rg * sbhh[768 + 512 + j]);
    out_sen[(size_t)b * 512 + 256 + j] = (1.f - zg) * ng;
}

// ---------------- fused 3 masked means over visual_fea (fp32 in d_out) ----------------
__global__ __launch_bounds__(256) void means_kernel(
    const float* __restrict__ vis, const float* __restrict__ loc, const int* __restrict__ v_len,
    float* __restrict__ leftm, float* __restrict__ rightm, float* __restrict__ gvm)
{
    int b = blockIdx.x, tid = threadIdx.x;
    int vl = v_len[b];
    float l0 = loc[b * 2], l1 = loc[b * 2 + 1];
    bool cond = l0 <= l1;
    float lf1 = cond ? l0 : 0.f;
    float rf0 = cond ? l1 : 1.f;
    float scale = (float)(vl - 1);
    int lS = 0;
    int lE = (int)floorf(lf1 * scale);
    int rS = (int)floorf(rf0 * scale);
    int rE = vl - 1;
    bool lok = lS <= lE, rok = rS <= rE;
    float lcnt = fmaxf(lok ? (float)(lE - lS + 1) : 0.f, 1.f);
    float rcnt = fmaxf(rok ? (float)(rE - rS + 1) : 0.f, 1.f);
    float gcnt = (float)vl;

    float sl[4] = {0, 0, 0, 0}, sr[4] = {0, 0, 0, 0}, sg[4] = {0, 0, 0, 0};
    for (int t = 0; t < 256; t++) {
        bool inL = lok && t >= lS && t <= lE;
        bool inR = rok && t >= rS && t <= rE;
        bool inG = t < vl;
        const float* row = vis + ((size_t)b * 256 + t) * 1024 + tid;
#pragma unroll
        for (int q = 0; q < 4; q++) {
            float v = row[q * 256];
            if (inL) sl[q] += v;
            if (inR) sr[q] += v;
            if (inG) sg[q] += v;
        }
    }
#pragma unroll
    for (int q = 0; q < 4; q++) {
        int j = tid + q * 256;
        leftm[(size_t)b * 1024 + j] = sl[q] / lcnt;
        rightm[(size_t)b * 1024 + j] = sr[q] / rcnt;
        gvm[(size_t)b * 1024 + j] = sg[q] / gcnt;
    }
}

// ---------------- concat misc: sen_fea copy, gv_fea copy, loc_fea ----------------
__global__ __launch_bounds__(256) void concat_misc_kernel(
    const float* __restrict__ out_sen, const float* __restrict__ gvm,
    const float* __restrict__ loc, const float* __restrict__ fc3w, const float* __restrict__ fc3b,
    float* __restrict__ concat)
{
    int b = blockIdx.x, tid = threadIdx.x;
    float* crow = concat + (size_t)b * 2624;
    for (int j = tid; j < 512; j += 256) crow[j] = out_sen[(size_t)b * 512 + j];
    for (int j = tid; j < 1024; j += 256) crow[512 + j] = gvm[(size_t)b * 1024 + j];
    float l0 = loc[b * 2], l1 = loc[b * 2 + 1];
    for (int o = tid; o < 64; o += 256)
        crow[2560 + o] = fmaxf(l0 * fc3w[o * 2] + l1 * fc3w[o * 2 + 1] + fc3b[o], 0.f);
}

// ---------------- s_proj = sen_fea @ fc2_w^T + fc2_b  (no relu) ----------------
// grid (16 n-tiles x 8 m-tiles); block: 16 batches x 32 outs, thread = (o,2 batches)
__global__ __launch_bounds__(256) void sproj_kernel(
    const float* __restrict__ out_sen, const float* __restrict__ fc2w,
    const float* __restrict__ fc2b, float* __restrict__ sproj)
{
    __shared__ float sf[16][512];
    int n0 = blockIdx.x * 32, m0 = blockIdx.y * 16;
    int tid = threadIdx.x;
    for (int i = tid; i < 16 * 512; i += 256) sf[i >> 9][i & 511] = out_sen[(size_t)(m0 + (i >> 9)) * 512 + (i & 511)];
    __syncthreads();
    int o = n0 + (tid & 31), bh = tid >> 5;
    const float* w = fc2w + (size_t)o * 512;
    float a0 = 0.f, a1 = 0.f;
    for (int k = 0; k < 512; k += 4) {
        f32x4 wv = *(const f32x4*)(const void*)(w + k);
#pragma unroll
        for (int q = 0; q < 4; q++) { a0 += sf[bh][k + q] * wv[q]; a1 += sf[bh + 8][k + q] * wv[q]; }
    }
    float bb = fc2b[o];
    sproj[(size_t)(m0 + bh) * 512 + o] = a0 + bb;
    sproj[(size_t)(m0 + bh + 8) * 512 + o] = a1 + bb;
}

// ---------------- l_vs / r_vs = relu((mean @ fc1_w^T + fc1_b) * s_proj) ----------------
__global__ __launch_bounds__(256) void fc1lr_kernel(
    const float* __restrict__ leftm, const float* __restrict__ rightm,
    const float* __restrict__ fc1w, const float* __restrict__ fc1b,
    const float* __restrict__ sproj, float* __restrict__ concat)
{
    __shared__ float lf[16][256], rf[16][256];
    int n0 = blockIdx.x * 32, m0 = blockIdx.y * 16;
    int tid = threadIdx.x;
    int o = n0 + (tid & 31), bh = tid >> 5;
    float aL0 = 0.f, aL1 = 0.f, aR0 = 0.f, aR1 = 0.f;
    for (int kc = 0; kc < 1024; kc += 256) {
        __syncthreads();
        for (int i = tid; i < 16 * 256; i += 256) {
            int bl = i >> 8, c = i & 255;
            lf[bl][c] = leftm[(size_t)(m0 + bl) * 1024 + kc + c];
            rf[bl][c] = rightm[(size_t)(m0 + bl) * 1024 + kc + c];
        }
        __syncthreads();
        const float* w = fc1w + (size_t)o * 1024 + kc;
        for (int k = 0; k < 256; k += 4) {
            f32x4 wv = *(const f32x4*)(const void*)(w + k);
#pragma unroll
            for (int q = 0; q < 4; q++) {
                float x = wv[q];
                aL0 += lf[bh][k + q] * x; aL1 += lf[bh + 8][k + q] * x;
                aR0 += rf[bh][k + q] * x; aR1 += rf[bh + 8][k + q] * x;
            }
        }
    }
    float bb = fc1b[o];
    float sp0 = sproj[(size_t)(m0 + bh) * 512 + o];
    float sp1 = sproj[(size_t)(m0 + bh + 8) * 512 + o];
    float* c0 = concat + (size_t)(m0 + bh) * 2624;
    float* c1 = concat + (size_t)(m0 + bh + 8) * 2624;
    c0[1536 + o] = fmaxf((aL0 + bb) * sp0, 0.f);
    c0[2048 + o] = fmaxf((aR0 + bb) * sp0, 0.f);
    c1[1536 + o] = fmaxf((aL1 + bb) * sp1, 0.f);
    c1[2048 + o] = fmaxf((aR1 + bb) * sp1, 0.f);
}

// ---------------- feature = relu(concat @ fc4_w^T + fc4_b) ----------------
// grid (32 n-tiles x 8 m-tiles); K=2624 staged in 4 chunks of 656
__global__ __launch_bounds__(256) void fc4_kernel(
    const float* __restrict__ concat, const float* __restrict__ fc4w,
    const float* __restrict__ fc4b, float* __restrict__ out_feat)
{
    __shared__ float cs[16][656];
    int n0 = blockIdx.x * 32, m0 = blockIdx.y * 16;
    int tid = threadIdx.x;
    int o = n0 + (tid & 31), bh = tid >> 5;
    float a0 = 0.f, a1 = 0.f;
    for (int kc = 0; kc < 2624; kc += 656) {
        __syncthreads();
        for (int i = tid; i < 16 * 656; i += 256) {
            int bl = i / 656, c = i - bl * 656;
            cs[bl][c] = concat[(size_t)(m0 + bl) * 2624 + kc + c];
        }
        __syncthreads();
        const float* w = fc4w + (size_t)o * 2624 + kc;
        for (int k = 0; k < 656; k += 4) {
            f32x4 wv = *(const f32x4*)(const void*)(w + k);
#pragma unroll
            for (int q = 0; q < 4; q++) { a0 += cs[bh][k + q] * wv[q]; a1 += cs[bh + 8][k + q] * wv[q]; }
        }
    }
    float bb = fc4b[o];
    out_feat[(size_t)(m0 + bh) * 1024 + o] = fmaxf(a0 + bb, 0.f);
    out_feat[(size_t)(m0 + bh + 8) * 1024 + o] = fmaxf(a1 + bb, 0.f);
}

extern "C" void kernel_launch(void* const* d_in, const int* in_sizes, int n_in,
                              void* d_out, int out_size, void* d_ws, size_t ws_size,
                              hipStream_t stream)
{
    (void)in_sizes; (void)n_in; (void)out_size; (void)ws_size;
    const float* gv   = (const float*)d_in[1];
    const float* sen  = (const float*)d_in[2];
    const float* loc  = (const float*)d_in[5];
    const int* lens   = (const int*)d_in[6];
    const int* vlen   = (const int*)d_in[7];
    const float* vwih = (const float*)d_in[8];
    const float* vwhh = (const float*)d_in[9];
    const float* vbih = (const float*)d_in[10];
    const float* vbhh = (const float*)d_in[11];
    const float* swih = (const float*)d_in[12];
    const float* swhh = (const float*)d_in[13];
    const float* sbih = (const float*)d_in[14];
    const float* sbhh = (const float*)d_in[15];
    const float* fc1w = (const float*)d_in[16];
    const float* fc1b = (const float*)d_in[17];
    const float* fc2w = (const float*)d_in[18];
    const float* fc2b = (const float*)d_in[19];
    const float* fc3w = (const float*)d_in[20];
    const float* fc3b = (const float*)d_in[21];
    const float* fc4w = (const float*)d_in[22];
    const float* fc4b = (const float*)d_in[23];

    float* out = (float*)d_out;
    float* out_vis  = out;                       // [128,256,1024]
    float* out_sen  = out + 33554432;            // [128,512]
    float* out_feat = out + 33619968;            // [128,1024]

    // ---- workspace plan (~19 MB) ----
    char* ws = (char*)d_ws;
    size_t off = 0;
    auto take = [&](size_t n) { void* p = ws + off; off += (n + 255) & ~(size_t)255; return p; };
    u16*   vwih_bf = (u16*)  take((size_t)3072 * 1024 * 2);
    u16*   vwhh_bf = (u16*)  take((size_t)3072 * 512 * 2);
    u16*   swihp   = (u16*)  take((size_t)768 * 320 * 2);    // fwd dir, padded 300->320
    u16*   swhh_bf = (u16*)  take((size_t)768 * 256 * 2);    // fwd dir
    u16*   senpad  = (u16*)  take((size_t)5120 * 320 * 2);   // padded 300->320
    float* hv_f    = (float*)take((size_t)2 * 131072 * 4);   // [parity][2dir][128][512]
    u16*   hv_b    = (u16*)  take((size_t)2 * 131072 * 2);
    float* hs_f    = (float*)take((size_t)2 * 32768 * 4);    // [parity][128][256]
    u16*   hs_b    = (u16*)  take((size_t)2 * 32768 * 2);
    float* leftm   = (float*)take((size_t)128 * 1024 * 4);
    float* rightm  = (float*)take((size_t)128 * 1024 * 4);
    float* gvm     = (float*)take((size_t)128 * 1024 * 4);
    float* sproj   = (float*)take((size_t)128 * 512 * 4);
    float* concat  = (float*)take((size_t)128 * 2624 * 4);

    // zero parity-0 h buffers
    hipMemsetAsync(hv_f, 0, 131072 * 4, stream);
    hipMemsetAsync(hv_b, 0, 131072 * 2, stream);
    hipMemsetAsync(hs_f, 0, 32768 * 4, stream);
    hipMemsetAsync(hs_b, 0, 32768 * 2, stream);

    // fp32 -> bf16 weight/input conversion (+ K padding to 16B multiples)
    cvt_pad<<<(3072 * 1024 + 255) / 256, 256, 0, stream>>>(vwih, vwih_bf, 3072, 1024, 1024);
    cvt_pad<<<(3072 * 512 + 255) / 256, 256, 0, stream>>>(vwhh, vwhh_bf, 3072, 512, 512);
    cvt_pad<<<(768 * 320 + 255) / 256, 256, 0, stream>>>(swih, swihp, 768, 300, 320);
    cvt_pad<<<(768 * 256 + 255) / 256, 256, 0, stream>>>(swhh, swhh_bf, 768, 256, 256);
    cvt_pad<<<(5120 * 320 + 255) / 256, 256, 0, stream>>>(sen, senpad, 5120, 300, 320);

    for (int s = 0; s < 256; s++) {
        int p = s & 1, q = 1 - p;
        int grid = (s < 40) ? 160 : 128;
        gru_step_fused<<<grid, 256, 0, stream>>>(s,
            gv, vwih_bf, vbih, vwhh_bf, vbhh,
            hv_b + (size_t)p * 131072, hv_f + (size_t)p * 131072,
            hv_b + (size_t)q * 131072, hv_f + (size_t)q * 131072,
            vlen, out_vis,
            senpad, swihp, sbih, swhh_bf, sbhh,
            hs_b + (size_t)p * 32768, hs_f + (size_t)p * 32768,
            hs_b + (size_t)q * 32768, hs_f + (size_t)q * 32768,
            lens);
    }

    senfea_kernel<<<128, 256, 0, stream>>>(hs_f, sen, swih, sbih, sbhh, lens, out_sen);
    means_kernel<<<128, 256, 0, stream>>>(out_vis, loc, vlen, leftm, rightm, gvm);
    concat_misc_kernel<<<128, 256, 0, stream>>>(out_sen, gvm, loc, fc3w, fc3b, concat);
    sproj_kernel<<<dim3(16, 8), 256, 0, stream>>>(out_sen, fc2w, fc2b, sproj);
    fc1lr_kernel<<<dim3(16, 8), 256, 0, stream>>>(leftm, rightm, fc1w, fc1b, sproj, concat);
    fc4_kernel<<<dim3(32, 8), 256, 0, stream>>>(concat, fc4w, fc4b, out_feat);
}

// Round 4
// 4307.808 us; speedup vs baseline: 1.9077x; 1.9077x over previous
//
#include <hip/hip_runtime.h>
#include <math.h>

typedef unsigned short u16;
typedef float f32x4 __attribute__((ext_vector_type(4)));
typedef __bf16 bf16x8 __attribute__((ext_vector_type(8)));
typedef u16 u16x4 __attribute__((ext_vector_type(4)));

#define DEVINL __device__ __forceinline__

DEVINL float sigm(float x) { return 1.f / (1.f + expf(-x)); }

DEVINL float b2f(u16 b) { unsigned u = ((unsigned)b) << 16; float f; __builtin_memcpy(&f, &u, 4); return f; }
DEVINL u16 f2b(float f) { __bf16 h = (__bf16)f; u16 bits; __builtin_memcpy(&bits, &h, 2); return bits; }

DEVINL bf16x8 ldA(const u16* p) { return *(const bf16x8*)(const void*)p; }
DEVINL bf16x8 ldA(const float* p) {
    f32x4 a = *(const f32x4*)(const void*)p;
    f32x4 b = *(const f32x4*)(const void*)(p + 4);
    bf16x8 r;
    r[0] = (__bf16)a[0]; r[1] = (__bf16)a[1]; r[2] = (__bf16)a[2]; r[3] = (__bf16)a[3];
    r[4] = (__bf16)b[0]; r[5] = (__bf16)b[1]; r[6] = (__bf16)b[2]; r[7] = (__bf16)b[3];
    return r;
}
DEVINL f32x4 mfma_bf16(bf16x8 a, bf16x8 b, f32x4 c) {
    return __builtin_amdgcn_mfma_f32_16x16x32_bf16(a, b, c, 0, 0, 0);
}
DEVINL void gload_lds16(const void* g, void* l) {
    __builtin_amdgcn_global_load_lds((__attribute__((address_space(1))) void*)(g),
                                     (__attribute__((address_space(3))) void*)(l), 16, 0, 0);
}

// ---------------- fp32 -> bf16 converters ----------------
__global__ __launch_bounds__(256) void cvt_pad(
    const float* __restrict__ src, u16* __restrict__ dst, int rows, int scols, int dcols)
{
    int idx = blockIdx.x * 256 + threadIdx.x;
    if (idx >= rows * dcols) return;
    int r = idx / dcols, c = idx - r * dcols;
    dst[idx] = (c < scols) ? f2b(src[(size_t)r * scols + c]) : (u16)0;
}
__global__ __launch_bounds__(256) void cvt4(
    const float* __restrict__ src, u16* __restrict__ dst, int n4)  // n4 = total/4
{
    int idx = blockIdx.x * 256 + threadIdx.x;
    if (idx >= n4) return;
    f32x4 v = *(const f32x4*)(const void*)(src + (size_t)idx * 4);
    u16x4 o; o[0] = f2b(v[0]); o[1] = f2b(v[1]); o[2] = f2b(v[2]); o[3] = f2b(v[3]);
    *(u16x4*)(void*)(dst + (size_t)idx * 4) = o;
}

// ---------------- big GEMM: C[M,N](bf16) = A[M,K](bf16) @ Bt[N,K]^T + bias[N](f32) ----------------
// m97 structure: 128x128 tile, BK=32, global_load_lds width=16, 16x16x32 MFMA.
// Requires M%128==0, N%128==0, K%32==0.
__global__ __launch_bounds__(256) void gemm_bt_bias(
    const u16* __restrict__ A, const u16* __restrict__ Bt,
    const float* __restrict__ bias, u16* __restrict__ C, int M, int N, int K)
{
    __shared__ __align__(16) u16 As[128 * 32];
    __shared__ __align__(16) u16 Bs[128 * 32];
    const int tid = threadIdx.x;
    const int lane = tid & 63, wv = tid >> 6;
    const int l15 = lane & 15, quad = lane >> 4;
    const int m0 = blockIdx.y * 128, n0 = blockIdx.x * 128;
    const int wm = (wv >> 1) * 64, wn = (wv & 1) * 64;

    f32x4 acc[4][4];
#pragma unroll
    for (int i = 0; i < 4; i++)
#pragma unroll
        for (int j = 0; j < 4; j++) acc[i][j] = f32x4{0.f, 0.f, 0.f, 0.f};

    for (int k0 = 0; k0 < K; k0 += 32) {
#pragma unroll
        for (int i = 0; i < 2; i++) {
            int c = i * 256 + tid;
            int row = c >> 2, kc = (c & 3) * 8;
            const u16* ga = A + (size_t)(m0 + row) * K + k0 + kc;
            const u16* gb = Bt + (size_t)(n0 + row) * K + k0 + kc;
            int lbase = (i * 256 + wv * 64) * 8;  // wave-uniform LDS base (elements)
            gload_lds16(ga, &As[lbase]);
            gload_lds16(gb, &Bs[lbase]);
        }
        __syncthreads();
        bf16x8 af[4], bfr[4];
#pragma unroll
        for (int mi = 0; mi < 4; mi++) af[mi] = ldA(&As[(wm + mi * 16 + l15) * 32 + quad * 8]);
#pragma unroll
        for (int ni = 0; ni < 4; ni++) bfr[ni] = ldA(&Bs[(wn + ni * 16 + l15) * 32 + quad * 8]);
#pragma unroll
        for (int mi = 0; mi < 4; mi++)
#pragma unroll
            for (int ni = 0; ni < 4; ni++)
                acc[mi][ni] = mfma_bf16(af[mi], bfr[ni], acc[mi][ni]);
        __syncthreads();
    }
#pragma unroll
    for (int mi = 0; mi < 4; mi++) {
        int row = m0 + wm + mi * 16 + quad * 4;
#pragma unroll
        for (int ni = 0; ni < 4; ni++) {
            int col = n0 + wn + ni * 16 + l15;
            float bv = bias[col];
#pragma unroll
            for (int r = 0; r < 4; r++)
                C[(size_t)(row + r) * N + col] = f2b(acc[mi][ni][r] + bv);
        }
    }
}

// ---------------- FAST recurrence step: gates = xp + h @ Whh ----------------
// xp (bf16) already contains x@Wih^T + b_ih.  Wave: 16 batches x 16 j x 3 gates.
template<int XPLD, int H, bool WOUT>
DEVINL void gru_tile_xp(int s, int T, int jblk, int mblk, int d,
    const u16* __restrict__ xp,     // [B*T, XPLD], pre-offset to dir (g*H + j indexing)
    const u16* __restrict__ whh,    // bf16 [3H, H], pre-offset to dir
    const float* __restrict__ bhh,  // f32 [3H], pre-offset to dir
    const u16* __restrict__ hbf_in, const float* __restrict__ hf_in,  // [128,H]
    u16* __restrict__ hbf_out, float* __restrict__ hf_out,
    const int* __restrict__ len, float* __restrict__ out, int tid)
{
    const int lane = tid & 63, wv = tid >> 6;
    const int l15 = lane & 15, quad = lane >> 4;
    const int m0 = mblk * 64 + wv * 16;
    const int j0 = jblk * 16;
    const int t = (d == 0) ? s : (T - 1 - s);

    f32x4 accr{0,0,0,0}, accz{0,0,0,0}, accn{0,0,0,0};
    const size_t ah = (size_t)(m0 + l15) * H;
    const size_t hr = (size_t)(j0 + l15) * H;
#pragma unroll 4
    for (int k0 = 0; k0 < H; k0 += 32) {
        bf16x8 a = ldA(hbf_in + ah + k0 + quad * 8);
        accr = mfma_bf16(a, ldA(whh + hr + k0 + quad * 8), accr);
        accz = mfma_bf16(a, ldA(whh + hr + (size_t)H * H + k0 + quad * 8), accz);
        accn = mfma_bf16(a, ldA(whh + hr + (size_t)2 * H * H + k0 + quad * 8), accn);
    }
    const int j = j0 + l15;
    const float bhr = bhh[j], bhz = bhh[H + j], bhn = bhh[2 * H + j];
#pragma unroll
    for (int r = 0; r < 4; r++) {
        int b = m0 + quad * 4 + r;
        size_t xb = ((size_t)b * T + t) * XPLD + j;
        float xr = b2f(xp[xb]);
        float xz = b2f(xp[xb + H]);
        float xn = b2f(xp[xb + 2 * H]);
        float rg = sigm(xr + accr[r] + bhr);
        float zg = sigm(xz + accz[r] + bhz);
        float ng = tanhf(xn + rg * (accn[r] + bhn));
        float hp = hf_in[(size_t)b * H + j];
        bool valid = t < len[b];
        float hn2 = valid ? ((1.f - zg) * ng + zg * hp) : hp;
        hf_out[(size_t)b * H + j] = hn2;
        hbf_out[(size_t)b * H + j] = f2b(hn2);
        if (WOUT)
            out[((size_t)b * T + t) * (2 * H) + (size_t)d * H + j] = valid ? hn2 : 0.f;
    }
}

__global__ __launch_bounds__(256) void gru_step_xp(int s,
    const u16* __restrict__ xpv, const u16* __restrict__ vwhh, const float* __restrict__ vbhh,
    const u16* __restrict__ hvi_b, const float* __restrict__ hvi_f,
    u16* __restrict__ hvo_b, float* __restrict__ hvo_f,
    const int* __restrict__ v_len, float* __restrict__ out_vis,
    const u16* __restrict__ xps, const u16* __restrict__ swhh, const float* __restrict__ sbhh,
    const u16* __restrict__ hsi_b, const float* __restrict__ hsi_f,
    u16* __restrict__ hso_b, float* __restrict__ hso_f,
    const int* __restrict__ lens)
{
    int bid = blockIdx.x;
    if (bid < 128) {
        int d = bid >> 6, jblk = (bid >> 1) & 31, mblk = bid & 1;
        gru_tile_xp<3072, 512, true>(s, 256, jblk, mblk, d,
            xpv + (size_t)d * 1536, vwhh + (size_t)d * 1536 * 512, vbhh + d * 1536,
            hvi_b + (size_t)d * 65536, hvi_f + (size_t)d * 65536,
            hvo_b + (size_t)d * 65536, hvo_f + (size_t)d * 65536,
            v_len, out_vis, threadIdx.x);
    } else {
        int b2 = bid - 128, jblk = b2 >> 1, mblk = b2 & 1;
        gru_tile_xp<768, 256, false>(s, 40, jblk, mblk, 0,
            xps, swhh, sbhh,
            hsi_b, hsi_f, hso_b, hso_f, lens, (float*)nullptr, threadIdx.x);
    }
}

// ---------------- SLOW fallback recurrence (Round-3, HW-proven) ----------------
template<int HIPAD, int H, bool WOUT, typename XT>
DEVINL void gru_tile_fused(int s, int T, int d, int jblk, int mblk,
    const XT* __restrict__ x,
    const u16* __restrict__ wih, const float* __restrict__ bih,
    const u16* __restrict__ whh, const float* __restrict__ bhh,
    const u16* __restrict__ hbf_in, const float* __restrict__ hf_in,
    u16* __restrict__ hbf_out, float* __restrict__ hf_out,
    const int* __restrict__ len, float* __restrict__ out, int tid)
{
    const int lane = tid & 63, wv = tid >> 6;
    const int l15 = lane & 15, quad = lane >> 4;
    const int m0 = mblk * 64 + wv * 16;
    const int j0 = jblk * 16;
    const int t = (d == 0) ? s : (T - 1 - s);

    f32x4 acc0{0,0,0,0}, acc1{0,0,0,0}, acc2{0,0,0,0}, acc3{0,0,0,0};
    const size_t ax = ((size_t)(m0 + l15) * T + t) * HIPAD;
    const size_t wr = (size_t)(j0 + l15) * HIPAD;
#pragma unroll 4
    for (int k0 = 0; k0 < HIPAD; k0 += 32) {
        bf16x8 a = ldA(x + ax + k0 + quad * 8);
        acc0 = mfma_bf16(a, ldA(wih + wr + k0 + quad * 8), acc0);
        acc1 = mfma_bf16(a, ldA(wih + wr + (size_t)H * HIPAD + k0 + quad * 8), acc1);
        acc2 = mfma_bf16(a, ldA(wih + wr + (size_t)2 * H * HIPAD + k0 + quad * 8), acc2);
    }
    const size_t ah = (size_t)(m0 + l15) * H;
    const size_t hr = (size_t)(j0 + l15) * H;
#pragma unroll 4
    for (int k0 = 0; k0 < H; k0 += 32) {
        bf16x8 a = ldA(hbf_in + ah + k0 + quad * 8);
        acc0 = mfma_bf16(a, ldA(whh + hr + k0 + quad * 8), acc0);
        acc1 = mfma_bf16(a, ldA(whh + hr + (size_t)H * H + k0 + quad * 8), acc1);
        acc3 = mfma_bf16(a, ldA(whh + hr + (size_t)2 * H * H + k0 + quad * 8), acc3);
    }
    const int j = j0 + l15;
    const float br  = bih[j]         + bhh[j];
    const float bz  = bih[H + j]     + bhh[H + j];
    const float bxn = bih[2 * H + j];
    const float bhn = bhh[2 * H + j];
#pragma unroll
    for (int r = 0; r < 4; r++) {
        int b = m0 + quad * 4 + r;
        float rg = sigm(acc0[r] + br);
        float zg = sigm(acc1[r] + bz);
        float ng = tanhf(acc2[r] + bxn + rg * (acc3[r] + bhn));
        float hp = hf_in[(size_t)b * H + j];
        bool valid = t < len[b];
        float hn2 = valid ? ((1.f - zg) * ng + zg * hp) : hp;
        hf_out[(size_t)b * H + j] = hn2;
        hbf_out[(size_t)b * H + j] = f2b(hn2);
        if (WOUT)
            out[((size_t)b * T + t) * (2 * H) + (size_t)d * H + j] = valid ? hn2 : 0.f;
    }
}

__global__ __launch_bounds__(256) void gru_step_fused(int s,
    const float* __restrict__ gv,
    const u16* __restrict__ vwih, const float* __restrict__ vbih,
    const u16* __restrict__ vwhh, const float* __restrict__ vbhh,
    const u16* __restrict__ hvi_b, const float* __restrict__ hvi_f,
    u16* __restrict__ hvo_b, float* __restrict__ hvo_f,
    const int* __restrict__ v_len, float* __restrict__ out_vis,
    const u16* __restrict__ senpad, const u16* __restrict__ swihp,
    const float* __restrict__ sbih, const u16* __restrict__ swhhb, const float* __restrict__ sbhh,
    const u16* __restrict__ hsi_b, const float* __restrict__ hsi_f,
    u16* __restrict__ hso_b, float* __restrict__ hso_f,
    const int* __restrict__ lens)
{
    int bid = blockIdx.x;
    if (bid < 128) {
        int d = bid >> 6, jblk = (bid >> 1) & 31, mblk = bid & 1;
        gru_tile_fused<1024, 512, true, float>(s, 256, d, jblk, mblk,
            gv, vwih + (size_t)d * 1536 * 1024, vbih + d * 1536,
            vwhh + (size_t)d * 1536 * 512, vbhh + d * 1536,
            hvi_b + (size_t)d * 65536, hvi_f + (size_t)d * 65536,
            hvo_b + (size_t)d * 65536, hvo_f + (size_t)d * 65536,
            v_len, out_vis, threadIdx.x);
    } else {
        int b2 = bid - 128, jblk = b2 >> 1, mblk = b2 & 1;
        gru_tile_fused<320, 256, false, u16>(s, 40, 0, jblk, mblk,
            senpad, swihp, sbih, swhhb, sbhh,
            hsi_b, hsi_f, hso_b, hso_f, lens, (float*)nullptr, threadIdx.x);
    }
}

// ---------------- sen_fea: fwd final h + bwd single-step-from-zero ----------------
__global__ __launch_bounds__(256) void senfea_kernel(
    const float* __restrict__ hs_f, const float* __restrict__ sen,
    const float* __restrict__ swih, const float* __restrict__ sbih, const float* __restrict__ sbhh,
    const int* __restrict__ lens, float* __restrict__ out_sen)
{
    __shared__ float xs[304];
    int b = blockIdx.x, j = threadIdx.x;
    int t = lens[b] - 1;
    for (int k = j; k < 300; k += 256) xs[k] = sen[((size_t)b * 40 + t) * 300 + k];
    __syncthreads();

    out_sen[(size_t)b * 512 + j] = hs_f[(size_t)b * 256 + j];

    float dot[3];
#pragma unroll
    for (int g = 0; g < 3; g++) {
        const float* w = swih + (size_t)(768 + g * 256 + j) * 300;
        float sacc = 0.f;
        for (int k = 0; k < 300; k += 4) {
            f32x4 wv = *(const f32x4*)(const void*)(w + k);
#pragma unroll
            for (int q = 0; q < 4; q++) sacc += xs[k + q] * wv[q];
        }
        dot[g] = sacc + sbih[768 + g * 256 + j];
    }
    float rg = sigm(dot[0] + sbhh[768 + j]);
    float zg = sigm(dot[1] + sbhh[768 + 256 + j]);
    float ng = tanhf(dot[2] + rg * sbhh[768 + 512 + j]);
    out_sen[(size_t)b * 512 + 256 + j] = (1.f - zg) * ng;
}

// ---------------- fused 3 masked means ----------------
__global__ __launch_bounds__(256) void means_kernel(
    const float* __restrict__ vis, const float* __restrict__ loc, const int* __restrict__ v_len,
    float* __restrict__ leftm, float* __restrict__ rightm, float* __restrict__ gvm)
{
    int b = blockIdx.x, tid = threadIdx.x;
    int vl = v_len[b];
    float l0 = loc[b * 2], l1 = loc[b * 2 + 1];
    bool cond = l0 <= l1;
    float lf1 = cond ? l0 : 0.f;
    float rf0 = cond ? l1 : 1.f;
    float scale = (float)(vl - 1);
    int lS = 0;
    int lE = (int)floorf(lf1 * scale);
    int rS = (int)floorf(rf0 * scale);
    int rE = vl - 1;
    bool lok = lS <= lE, rok = rS <= rE;
    float lcnt = fmaxf(lok ? (float)(lE - lS + 1) : 0.f, 1.f);
    float rcnt = fmaxf(rok ? (float)(rE - rS + 1) : 0.f, 1.f);
    float gcnt = (float)vl;

    float sl[4] = {0, 0, 0, 0}, sr[4] = {0, 0, 0, 0}, sg[4] = {0, 0, 0, 0};
    for (int t = 0; t < 256; t++) {
        bool inL = lok && t >= lS && t <= lE;
        bool inR = rok && t >= rS && t <= rE;
        bool inG = t < vl;
        const float* row = vis + ((size_t)b * 256 + t) * 1024 + tid;
#pragma unroll
        for (int q = 0; q < 4; q++) {
            float v = row[q * 256];
            if (inL) sl[q] += v;
            if (inR) sr[q] += v;
            if (inG) sg[q] += v;
        }
    }
#pragma unroll
    for (int q = 0; q < 4; q++) {
        int j = tid + q * 256;
        leftm[(size_t)b * 1024 + j] = sl[q] / lcnt;
        rightm[(size_t)b * 1024 + j] = sr[q] / rcnt;
        gvm[(size_t)b * 1024 + j] = sg[q] / gcnt;
    }
}

// ---------------- concat misc ----------------
__global__ __launch_bounds__(256) void concat_misc_kernel(
    const float* __restrict__ out_sen, const float* __restrict__ gvm,
    const float* __restrict__ loc, const float* __restrict__ fc3w, const float* __restrict__ fc3b,
    float* __restrict__ concat)
{
    int b = blockIdx.x, tid = threadIdx.x;
    float* crow = concat + (size_t)b * 2624;
    for (int j = tid; j < 512; j += 256) crow[j] = out_sen[(size_t)b * 512 + j];
    for (int j = tid; j < 1024; j += 256) crow[512 + j] = gvm[(size_t)b * 1024 + j];
    float l0 = loc[b * 2], l1 = loc[b * 2 + 1];
    for (int o = tid; o < 64; o += 256)
        crow[2560 + o] = fmaxf(l0 * fc3w[o * 2] + l1 * fc3w[o * 2 + 1] + fc3b[o], 0.f);
}

// ---------------- s_proj ----------------
__global__ __launch_bounds__(256) void sproj_kernel(
    const float* __restrict__ out_sen, const float* __restrict__ fc2w,
    const float* __restrict__ fc2b, float* __restrict__ sproj)
{
    __shared__ float sf[16][512];
    int n0 = blockIdx.x * 32, m0 = blockIdx.y * 16;
    int tid = threadIdx.x;
    for (int i = tid; i < 16 * 512; i += 256) sf[i >> 9][i & 511] = out_sen[(size_t)(m0 + (i >> 9)) * 512 + (i & 511)];
    __syncthreads();
    int o = n0 + (tid & 31), bh = tid >> 5;
    const float* w = fc2w + (size_t)o * 512;
    float a0 = 0.f, a1 = 0.f;
    for (int k = 0; k < 512; k += 4) {
        f32x4 wv = *(const f32x4*)(const void*)(w + k);
#pragma unroll
        for (int q = 0; q < 4; q++) { a0 += sf[bh][k + q] * wv[q]; a1 += sf[bh + 8][k + q] * wv[q]; }
    }
    float bb = fc2b[o];
    sproj[(size_t)(m0 + bh) * 512 + o] = a0 + bb;
    sproj[(size_t)(m0 + bh + 8) * 512 + o] = a1 + bb;
}

// ---------------- l_vs / r_vs ----------------
__global__ __launch_bounds__(256) void fc1lr_kernel(
    const float* __restrict__ leftm, const float* __restrict__ rightm,
    const float* __restrict__ fc1w, const float* __restrict__ fc1b,
    const float* __restrict__ sproj, float* __restrict__ concat)
{
    __shared__ float lf[16][256], rf[16][256];
    int n0 = blockIdx.x * 32, m0 = blockIdx.y * 16;
    int tid = threadIdx.x;
    int o = n0 + (tid & 31), bh = tid >> 5;
    float aL0 = 0.f, aL1 = 0.f, aR0 = 0.f, aR1 = 0.f;
    for (int kc = 0; kc < 1024; kc += 256) {
        __syncthreads();
        for (int i = tid; i < 16 * 256; i += 256) {
            int bl = i >> 8, c = i & 255;
            lf[bl][c] = leftm[(size_t)(m0 + bl) * 1024 + kc + c];
            rf[bl][c] = rightm[(size_t)(m0 + bl) * 1024 + kc + c];
        }
        __syncthreads();
        const float* w = fc1w + (size_t)o * 1024 + kc;
        for (int k = 0; k < 256; k += 4) {
            f32x4 wv = *(const f32x4*)(const void*)(w + k);
#pragma unroll
            for (int q = 0; q < 4; q++) {
                float x = wv[q];
                aL0 += lf[bh][k + q] * x; aL1 += lf[bh + 8][k + q] * x;
                aR0 += rf[bh][k + q] * x; aR1 += rf[bh + 8][k + q] * x;
            }
        }
    }
    float bb = fc1b[o];
    float sp0 = sproj[(size_t)(m0 + bh) * 512 + o];
    float sp1 = sproj[(size_t)(m0 + bh + 8) * 512 + o];
    float* c0 = concat + (size_t)(m0 + bh) * 2624;
    float* c1 = concat + (size_t)(m0 + bh + 8) * 2624;
    c0[1536 + o] = fmaxf((aL0 + bb) * sp0, 0.f);
    c0[2048 + o] = fmaxf((aR0 + bb) * sp0, 0.f);
    c1[1536 + o] = fmaxf((aL1 + bb) * sp1, 0.f);
    c1[2048 + o] = fmaxf((aR1 + bb) * sp1, 0.f);
}

// ---------------- fc4 ----------------
__global__ __launch_bounds__(256) void fc4_kernel(
    const float* __restrict__ concat, const float* __restrict__ fc4w,
    const float* __restrict__ fc4b, float* __restrict__ out_feat)
{
    __shared__ float cs[16][656];
    int n0 = blockIdx.x * 32, m0 = blockIdx.y * 16;
    int tid = threadIdx.x;
    int o = n0 + (tid & 31), bh = tid >> 5;
    float a0 = 0.f, a1 = 0.f;
    for (int kc = 0; kc < 2624; kc += 656) {
        __syncthreads();
        for (int i = tid; i < 16 * 656; i += 256) {
            int bl = i / 656, c = i - bl * 656;
            cs[bl][c] = concat[(size_t)(m0 + bl) * 2624 + kc + c];
        }
        __syncthreads();
        const float* w = fc4w + (size_t)o * 2624 + kc;
        for (int k = 0; k < 656; k += 4) {
            f32x4 wv = *(const f32x4*)(const void*)(w + k);
#pragma unroll
            for (int q = 0; q < 4; q++) { a0 += cs[bh][k + q] * wv[q]; a1 += cs[bh + 8][k + q] * wv[q]; }
        }
    }
    float bb = fc4b[o];
    out_feat[(size_t)(m0 + bh) * 1024 + o] = fmaxf(a0 + bb, 0.f);
    out_feat[(size_t)(m0 + bh + 8) * 1024 + o] = fmaxf(a1 + bb, 0.f);
}

extern "C" void kernel_launch(void* const* d_in, const int* in_sizes, int n_in,
                              void* d_out, int out_size, void* d_ws, size_t ws_size,
                              hipStream_t stream)
{
    (void)in_sizes; (void)n_in; (void)out_size;
    const float* gv   = (const float*)d_in[1];
    const float* sen  = (const float*)d_in[2];
    const float* loc  = (const float*)d_in[5];
    const int* lens   = (const int*)d_in[6];
    const int* vlen   = (const int*)d_in[7];
    const float* vwih = (const float*)d_in[8];
    const float* vwhh = (const float*)d_in[9];
    const float* vbih = (const float*)d_in[10];
    const float* vbhh = (const float*)d_in[11];
    const float* swih = (const float*)d_in[12];
    const float* swhh = (const float*)d_in[13];
    const float* sbih = (const float*)d_in[14];
    const float* sbhh = (const float*)d_in[15];
    const float* fc1w = (const float*)d_in[16];
    const float* fc1b = (const float*)d_in[17];
    const float* fc2w = (const float*)d_in[18];
    const float* fc2b = (const float*)d_in[19];
    const float* fc3w = (const float*)d_in[20];
    const float* fc3b = (const float*)d_in[21];
    const float* fc4w = (const float*)d_in[22];
    const float* fc4b = (const float*)d_in[23];

    float* out = (float*)d_out;
    float* out_vis  = out;
    float* out_sen  = out + 33554432;
    float* out_feat = out + 33619968;

    char* ws = (char*)d_ws;
    size_t off = 0;
    auto take = [&](size_t n) { void* p = ws + off; off += (n + 255) & ~(size_t)255; return p; };

    // ---- fast-path plan (~295 MB) ----
    u16*   gv_bf   = (u16*)  take((size_t)32768 * 1024 * 2);
    u16*   xpv     = (u16*)  take((size_t)32768 * 3072 * 2);
    u16*   vwih_bf = (u16*)  take((size_t)3072 * 1024 * 2);
    u16*   vwhh_bf = (u16*)  take((size_t)3072 * 512 * 2);
    u16*   swihp   = (u16*)  take((size_t)768 * 320 * 2);
    u16*   swhh_bf = (u16*)  take((size_t)768 * 256 * 2);
    u16*   senpad  = (u16*)  take((size_t)5120 * 320 * 2);
    u16*   xps     = (u16*)  take((size_t)5120 * 768 * 2);
    float* hv_f    = (float*)take((size_t)2 * 131072 * 4);
    u16*   hv_b    = (u16*)  take((size_t)2 * 131072 * 2);
    float* hs_f    = (float*)take((size_t)2 * 32768 * 4);
    u16*   hs_b    = (u16*)  take((size_t)2 * 32768 * 2);
    float* leftm   = (float*)take((size_t)128 * 1024 * 4);
    float* rightm  = (float*)take((size_t)128 * 1024 * 4);
    float* gvm     = (float*)take((size_t)128 * 1024 * 4);
    float* sproj   = (float*)take((size_t)128 * 512 * 4);
    float* concat  = (float*)take((size_t)128 * 2624 * 4);
    bool fast = (off <= ws_size);

    if (!fast) {
        // ---- slow-path re-plan from 0 (~19 MB, Round-3 proven) ----
        off = 0;
        vwih_bf = (u16*)  take((size_t)3072 * 1024 * 2);
        vwhh_bf = (u16*)  take((size_t)3072 * 512 * 2);
        swihp   = (u16*)  take((size_t)768 * 320 * 2);
        swhh_bf = (u16*)  take((size_t)768 * 256 * 2);
        senpad  = (u16*)  take((size_t)5120 * 320 * 2);
        hv_f    = (float*)take((size_t)2 * 131072 * 4);
        hv_b    = (u16*)  take((size_t)2 * 131072 * 2);
        hs_f    = (float*)take((size_t)2 * 32768 * 4);
        hs_b    = (u16*)  take((size_t)2 * 32768 * 2);
        leftm   = (float*)take((size_t)128 * 1024 * 4);
        rightm  = (float*)take((size_t)128 * 1024 * 4);
        gvm     = (float*)take((size_t)128 * 1024 * 4);
        sproj   = (float*)take((size_t)128 * 512 * 4);
        concat  = (float*)take((size_t)128 * 2624 * 4);
    }

    hipMemsetAsync(hv_f, 0, 131072 * 4, stream);
    hipMemsetAsync(hv_b, 0, 131072 * 2, stream);
    hipMemsetAsync(hs_f, 0, 32768 * 4, stream);
    hipMemsetAsync(hs_b, 0, 32768 * 2, stream);

    // weight conversions (both paths)
    cvt4<<<(3072 * 1024 / 4 + 255) / 256, 256, 0, stream>>>(vwih, vwih_bf, 3072 * 1024 / 4);
    cvt4<<<(3072 * 512 / 4 + 255) / 256, 256, 0, stream>>>(vwhh, vwhh_bf, 3072 * 512 / 4);
    cvt_pad<<<(768 * 320 + 255) / 256, 256, 0, stream>>>(swih, swihp, 768, 300, 320);
    cvt4<<<(768 * 256 / 4 + 255) / 256, 256, 0, stream>>>(swhh, swhh_bf, 768 * 256 / 4);
    cvt_pad<<<(5120 * 320 + 255) / 256, 256, 0, stream>>>(sen, senpad, 5120, 300, 320);

    if (fast) {
        cvt4<<<(32768 * 1024 / 4 + 255) / 256, 256, 0, stream>>>(gv, gv_bf, 32768 * 1024 / 4);
        // xpv[M=32768, N=3072] = gv_bf @ vwih_bf^T + vbih
        gemm_bt_bias<<<dim3(3072 / 128, 32768 / 128), 256, 0, stream>>>(
            gv_bf, vwih_bf, vbih, xpv, 32768, 3072, 1024);
        // xps[M=5120, N=768] = senpad @ swihp^T + sbih (fwd dir)
        gemm_bt_bias<<<dim3(768 / 128, 5120 / 128), 256, 0, stream>>>(
            senpad, swihp, sbih, xps, 5120, 768, 320);

        for (int s = 0; s < 256; s++) {
            int p = s & 1, q = 1 - p;
            int grid = (s < 40) ? 160 : 128;
            gru_step_xp<<<grid, 256, 0, stream>>>(s,
                xpv, vwhh_bf, vbhh,
                hv_b + (size_t)p * 131072, hv_f + (size_t)p * 131072,
                hv_b + (size_t)q * 131072, hv_f + (size_t)q * 131072,
                vlen, out_vis,
                xps, swhh_bf, sbhh,
                hs_b + (size_t)p * 32768, hs_f + (size_t)p * 32768,
                hs_b + (size_t)q * 32768, hs_f + (size_t)q * 32768,
                lens);
        }
    } else {
        for (int s = 0; s < 256; s++) {
            int p = s & 1, q = 1 - p;
            int grid = (s < 40) ? 160 : 128;
            gru_step_fused<<<grid, 256, 0, stream>>>(s,
                gv, vwih_bf, vbih, vwhh_bf, vbhh,
                hv_b + (size_t)p * 131072, hv_f + (size_t)p * 131072,
                hv_b + (size_t)q * 131072, hv_f + (size_t)q * 131072,
                vlen, out_vis,
                senpad, swihp, sbih, swhh_bf, sbhh,
                hs_b + (size_t)p * 32768, hs_f + (size_t)p * 32768,
                hs_b + (size_t)q * 32768, hs_f + (size_t)q * 32768,
                lens);
        }
    }

    senfea_kernel<<<128, 256, 0, stream>>>(hs_f, sen, swih, sbih, sbhh, lens, out_sen);
    means_kernel<<<128, 256, 0, stream>>>(out_vis, loc, vlen, leftm, rightm, gvm);
    concat_misc_kernel<<<128, 256, 0, stream>>>(out_sen, gvm, loc, fc3w, fc3b, concat);
    sproj_kernel<<<dim3(16, 8), 256, 0, stream>>>(out_sen, fc2w, fc2b, sproj);
    fc1lr_kernel<<<dim3(16, 8), 256, 0, stream>>>(leftm, rightm, fc1w, fc1b, sproj, concat);
    fc4_kernel<<<dim3(32, 8), 256, 0, stream>>>(concat, fc4w, fc4b, out_feat);
}